// Round 13
// baseline (724.135 us; speedup 1.0000x reference)
//
#include <hip/hip_runtime.h>
#include <hip/hip_cooperative_groups.h>
#include <cmath>

namespace cg = cooperative_groups;

#define NFEAT_IN 128
#define NFEAT_H 64
#define BN_EPS 1e-5f
#define SCAP 2560   // per-bucket capacity (mean 2046, +11 sigma)
#define EPB 8192    // edges per block in block_append
#define NBMAX 800   // LDS bucket-table limit

typedef unsigned short ushort_t;
typedef unsigned int uint_t;
typedef __attribute__((ext_vector_type(8))) short short8v;
typedef __attribute__((ext_vector_type(4))) float f32x4;

__device__ inline float b2f(ushort_t u) {
    return __uint_as_float(((uint_t)u) << 16);
}

__device__ inline ushort_t f2b(float f) {
    uint_t x = __float_as_uint(f);
    return (ushort_t)((x + 0x7FFFu + ((x >> 16) & 1u)) >> 16);  // RNE
}

// ---------------- CSR build ----------------

__global__ __launch_bounds__(256) void block_append_kernel(const int* __restrict__ src,
                                                           const int* __restrict__ dst,
                                                           int* __restrict__ deg_s,
                                                           int* __restrict__ curD,
                                                           uint_t* __restrict__ dbuf,
                                                           int E, int NB) {
    __shared__ int lcnt[NBMAX];
    __shared__ int lcur[NBMAX];
    int t = threadIdx.x;
    int e0 = blockIdx.x * EPB;
    int e1 = min(e0 + EPB, E);
    for (int i = t; i < NB; i += 256) lcnt[i] = 0;
    __syncthreads();
    for (int e = e0 + t; e < e1; e += 256)
        atomicAdd(&lcnt[dst[e] >> 7], 1);
    __syncthreads();
    for (int i = t; i < NB; i += 256) {
        int c = lcnt[i];
        lcur[i] = (c > 0) ? atomicAdd(&curD[i * 16], c) : 0;
    }
    __syncthreads();
    for (int e = e0 + t; e < e1; e += 256) {
        int s = src[e], d = dst[e];
        atomicAdd(&deg_s[s], 1);
        int pos = atomicAdd(&lcur[d >> 7], 1);
        if (pos < SCAP) dbuf[(long long)(d >> 7) * SCAP + pos] = ((uint_t)s << 7) | (uint_t)(d & 127);
    }
}

// fallback if NB > NBMAX
__global__ __launch_bounds__(256) void deg_append_kernel(const int* __restrict__ src,
                                                         const int* __restrict__ dst,
                                                         int* __restrict__ deg_s,
                                                         int* __restrict__ curD,
                                                         uint_t* __restrict__ dbuf, int E) {
    int e = blockIdx.x * 256 + threadIdx.x;
    if (e < E) {
        int s = src[e], d = dst[e];
        atomicAdd(&deg_s[s], 1);
        int pD = atomicAdd(&curD[(d >> 7) * 16], 1);
        if (pD < SCAP) dbuf[(long long)(d >> 7) * SCAP + pD] = ((uint_t)s << 7) | (uint_t)(d & 127);
    }
}

__global__ __launch_bounds__(256) void bucket_hist_kernel(const uint_t* __restrict__ dbuf,
                                                          const int* __restrict__ curD,
                                                          int* __restrict__ deg_d, int N) {
    __shared__ int hist[128];
    int bb = blockIdx.x;
    int t = threadIdx.x;
    if (t < 128) hist[t] = 0;
    __syncthreads();
    int cnt = curD[bb * 16];
    if (cnt > SCAP) cnt = SCAP;
    long long base = (long long)bb * SCAP;
    for (int i = t; i < cnt; i += 256) atomicAdd(&hist[dbuf[base + i] & 127], 1);
    __syncthreads();
    if (t < 128) {
        int node = bb * 128 + t;
        if (node < N) deg_d[node] = hist[t];
    }
}

__global__ __launch_bounds__(256) void norm_scan_kernel(const int* __restrict__ deg_s,
                                                        const int* __restrict__ deg_d,
                                                        float* __restrict__ norm_s,
                                                        float* __restrict__ norm_d,
                                                        int* __restrict__ start,
                                                        int* __restrict__ counter,
                                                        float* __restrict__ stats, int N) {
    int tid = threadIdx.x;
    int i = blockIdx.x * 256 + tid;
    if (blockIdx.x == 0 && tid < 128) stats[tid] = 0.f;
    int lane = tid & 63, w = tid >> 6;
    int ds = 0, dd = 0;
    if (i < N) { ds = deg_s[i]; dd = deg_d[i]; }
    int pd = (dd + 7) & ~7;

    int x = pd;
#pragma unroll
    for (int off = 1; off < 64; off <<= 1) {
        int y = __shfl_up(x, off, 64);
        if (lane >= off) x += y;
    }
    __shared__ int wsum[4];
    __shared__ int blockbase;
    if (lane == 63) wsum[w] = x;
    __syncthreads();
    if (tid == 0)
        blockbase = atomicAdd(counter, wsum[0] + wsum[1] + wsum[2] + wsum[3]);
    __syncthreads();
    int base = blockbase;
    for (int ww = 0; ww < w; ++ww) base += wsum[ww];
    int st = base + x - pd;

    if (i < N) {
        norm_s[i] = rsqrtf((float)(ds > 1 ? ds : 1));
        norm_d[i] = rsqrtf((float)(dd > 1 ? dd : 1));
        start[i] = st;
    }
}

// per-bucket 2-pass scatter: col entries range-sorted by src quartile within each node
// segment; emits per-node range counts packed in uint2 (4 x 16-bit).
__global__ __launch_bounds__(256) void bucket_scatter2_kernel(const uint_t* __restrict__ dbuf,
                                                              const int* __restrict__ curD,
                                                              const int* __restrict__ start,
                                                              int* __restrict__ col,
                                                              uint2* __restrict__ rcnt,
                                                              int N, int Q) {
    __shared__ int cnt4[128][4];
    __shared__ int cur[128][4];
    int b = blockIdx.x, t = threadIdx.x;
    if (t < 128) { cnt4[t][0] = 0; cnt4[t][1] = 0; cnt4[t][2] = 0; cnt4[t][3] = 0; }
    __syncthreads();
    int cnt = curD[b * 16];
    if (cnt > SCAP) cnt = SCAP;
    long long base = (long long)b * SCAP;
    int Q2 = 2 * Q, Q3 = 3 * Q;
    for (int i = t; i < cnt; i += 256) {
        uint_t p = dbuf[base + i];
        int d0 = (int)(p & 127u);
        int s = (int)(p >> 7);
        int r = (s >= Q) + (s >= Q2) + (s >= Q3);
        atomicAdd(&cnt4[d0][r], 1);
    }
    __syncthreads();
    if (t < 128) {
        int node = b * 128 + t;
        int st = (node < N) ? start[node] : 0;
        int c0 = cnt4[t][0], c1 = cnt4[t][1], c2 = cnt4[t][2], c3 = cnt4[t][3];
        cur[t][0] = st;
        cur[t][1] = st + c0;
        cur[t][2] = st + c0 + c1;
        cur[t][3] = st + c0 + c1 + c2;
        if (node < N)
            rcnt[node] = make_uint2((uint_t)c0 | ((uint_t)c1 << 16),
                                    (uint_t)c2 | ((uint_t)c3 << 16));
    }
    __syncthreads();
    for (int i = t; i < cnt; i += 256) {
        uint_t p = dbuf[base + i];
        int d0 = (int)(p & 127u);
        int s = (int)(p >> 7);
        int r = (s >= Q) + (s >= Q2) + (s >= Q3);
        int off = atomicAdd(&cur[d0][r], 1);
        col[off] = s;
    }
}

// ---------------- MFMA GEMMs (R7-verified) ----------------

__global__ __launch_bounds__(256) void gemm1_mfma(const float* __restrict__ x,
                                                  const float* __restrict__ W,
                                                  const float* __restrict__ norm,
                                                  ushort_t* __restrict__ out, int n) {
    constexpr int K = 128;
    __shared__ ushort_t sWh[64 * K];
    __shared__ ushort_t sWl[64 * K];
    int tid = threadIdx.x;
    for (int i = tid; i < K * 64; i += 256) {
        int k = i >> 6, f = i & 63;
        float v = W[i];
        ushort_t hi = f2b(v);
        ushort_t lo = f2b(v - b2f(hi));
        int idx = f * K + (((k >> 3) ^ (f & 7)) << 3) + (k & 7);
        sWh[idx] = hi;
        sWl[idx] = lo;
    }
    int w = tid >> 6, l = tid & 63, g = l >> 4;
    int rA = blockIdx.x * 64 + w * 16 + (l & 15);
    f32x4 acc[4];
#pragma unroll
    for (int nt = 0; nt < 4; ++nt) acc[nt] = (f32x4){0.f, 0.f, 0.f, 0.f};
    __syncthreads();

#pragma unroll
    for (int ks = 0; ks < K / 32; ++ks) {
        float av[8];
        if (rA < n) {
            const float* px = x + (long long)rA * K + ks * 32 + g * 8;
            float4 p0 = *(const float4*)px;
            float4 p1 = *(const float4*)(px + 4);
            av[0] = p0.x; av[1] = p0.y; av[2] = p0.z; av[3] = p0.w;
            av[4] = p1.x; av[5] = p1.y; av[6] = p1.z; av[7] = p1.w;
        } else {
#pragma unroll
            for (int j = 0; j < 8; ++j) av[j] = 0.f;
        }
        short8v ah, al;
#pragma unroll
        for (int j = 0; j < 8; ++j) {
            ushort_t h = f2b(av[j]);
            ah[j] = (short)h;
            al[j] = (short)f2b(av[j] - b2f(h));
        }
#pragma unroll
        for (int nt = 0; nt < 4; ++nt) {
            int f = nt * 16 + (l & 15);
            int c = (ks * 4 + g) ^ (f & 7);
            short8v bh = *(const short8v*)&sWh[f * K + (c << 3)];
            short8v bl = *(const short8v*)&sWl[f * K + (c << 3)];
            acc[nt] = __builtin_amdgcn_mfma_f32_16x16x32_bf16(ah, bh, acc[nt], 0, 0, 0);
            acc[nt] = __builtin_amdgcn_mfma_f32_16x16x32_bf16(ah, bl, acc[nt], 0, 0, 0);
            acc[nt] = __builtin_amdgcn_mfma_f32_16x16x32_bf16(al, bh, acc[nt], 0, 0, 0);
        }
    }
    int rb = blockIdx.x * 64 + w * 16 + g * 4;
    float nv[4];
#pragma unroll
    for (int j = 0; j < 4; ++j) {
        int r = rb + j;
        nv[j] = (r < n) ? norm[r] : 0.f;
    }
#pragma unroll
    for (int nt = 0; nt < 4; ++nt) {
        int cc = nt * 16 + (l & 15);
#pragma unroll
        for (int j = 0; j < 4; ++j) {
            int r = rb + j;
            if (r < n) out[(long long)r * 64 + cc] = f2b(acc[nt][j] * nv[j]);
        }
    }
}

__global__ __launch_bounds__(256) void gemm2_mfma(const ushort_t* __restrict__ x,
                                                  const float* __restrict__ W,
                                                  const float* __restrict__ coef,
                                                  const float* __restrict__ biasK,
                                                  const float* __restrict__ norm,
                                                  ushort_t* __restrict__ out, int n) {
    constexpr int K = 64;
    __shared__ ushort_t sWh[64 * K];
    __shared__ ushort_t sWl[64 * K];
    int tid = threadIdx.x;
    for (int i = tid; i < K * 64; i += 256) {
        int k = i >> 6, f = i & 63;
        float v = coef[k] * W[i];
        ushort_t hi = f2b(v);
        ushort_t lo = f2b(v - b2f(hi));
        int idx = f * K + (((k >> 3) ^ (f & 7)) << 3) + (k & 7);
        sWh[idx] = hi;
        sWl[idx] = lo;
    }
    int w = tid >> 6, l = tid & 63, g = l >> 4;
    int rA = blockIdx.x * 64 + w * 16 + (l & 15);
    f32x4 acc[4];
#pragma unroll
    for (int nt = 0; nt < 4; ++nt) acc[nt] = (f32x4){0.f, 0.f, 0.f, 0.f};
    __syncthreads();

#pragma unroll
    for (int ks = 0; ks < 2; ++ks) {
        short8v ah;
        if (rA < n) {
            uint4 u = *(const uint4*)(x + (long long)rA * 64 + ks * 32 + g * 8);
            union { uint4 u; short8v s; } cvt;
            cvt.u = u;
            ah = cvt.s;
        } else {
#pragma unroll
            for (int j = 0; j < 8; ++j) ah[j] = 0;
        }
#pragma unroll
        for (int nt = 0; nt < 4; ++nt) {
            int f = nt * 16 + (l & 15);
            int c = (ks * 4 + g) ^ (f & 7);
            short8v bh = *(const short8v*)&sWh[f * K + (c << 3)];
            short8v bl = *(const short8v*)&sWl[f * K + (c << 3)];
            acc[nt] = __builtin_amdgcn_mfma_f32_16x16x32_bf16(ah, bh, acc[nt], 0, 0, 0);
            acc[nt] = __builtin_amdgcn_mfma_f32_16x16x32_bf16(ah, bl, acc[nt], 0, 0, 0);
        }
    }
    int rb = blockIdx.x * 64 + w * 16 + g * 4;
    float nv[4];
#pragma unroll
    for (int j = 0; j < 4; ++j) {
        int r = rb + j;
        nv[j] = (r < n) ? norm[r] : 0.f;
    }
#pragma unroll
    for (int nt = 0; nt < 4; ++nt) {
        int cc = nt * 16 + (l & 15);
        float bk = biasK[cc];
#pragma unroll
        for (int j = 0; j < 4; ++j) {
            int r = rb + j;
            if (r < n) out[(long long)r * 64 + cc] = f2b((acc[nt][j] + bk) * nv[j]);
        }
    }
}

// ---------------- per-row int8 quantization of h ----------------
__global__ __launch_bounds__(256) void quant8_kernel(const ushort_t* __restrict__ h,
                                                     uint2* __restrict__ q8,
                                                     float* __restrict__ qs, int N) {
    int tid = threadIdx.x;
    int w = tid >> 6, lane = tid & 63;
    int j = lane & 7;
    int row = blockIdx.x * 32 + w * 8 + (lane >> 3);
    if (row >= N) return;
    uint4 u = ((const uint4*)(h + (long long)row * 64))[j];
    float v[8];
    v[0] = __uint_as_float(u.x << 16);
    v[1] = __uint_as_float(u.x & 0xFFFF0000u);
    v[2] = __uint_as_float(u.y << 16);
    v[3] = __uint_as_float(u.y & 0xFFFF0000u);
    v[4] = __uint_as_float(u.z << 16);
    v[5] = __uint_as_float(u.z & 0xFFFF0000u);
    v[6] = __uint_as_float(u.w << 16);
    v[7] = __uint_as_float(u.w & 0xFFFF0000u);
    float m = 0.f;
#pragma unroll
    for (int i = 0; i < 8; ++i) m = fmaxf(m, fabsf(v[i]));
    m = fmaxf(m, __shfl_xor(m, 1, 64));
    m = fmaxf(m, __shfl_xor(m, 2, 64));
    m = fmaxf(m, __shfl_xor(m, 4, 64));
    float inv = (m > 0.f) ? 127.f / m : 0.f;
    if (j == 0) qs[row] = (m > 0.f) ? m * (1.f / 127.f) : 0.f;
    int q[8];
#pragma unroll
    for (int i = 0; i < 8; ++i) q[i] = __float2int_rn(v[i] * inv);
    uint2 p;
    p.x = (uint_t)(q[0] & 255) | ((uint_t)(q[1] & 255) << 8) |
          ((uint_t)(q[2] & 255) << 16) | ((uint_t)q[3] << 24);
    p.y = (uint_t)(q[4] & 255) | ((uint_t)(q[5] & 255) << 8) |
          ((uint_t)(q[6] & 255) << 16) | ((uint_t)q[7] << 24);
    q8[(long long)row * 8 + j] = p;
}

__device__ inline void acc_i8(float* acc, uint2 u, float sc) {
    acc[0] += sc * (float)(int)(signed char)(u.x);
    acc[1] += sc * (float)(int)(signed char)(u.x >> 8);
    acc[2] += sc * (float)(int)(signed char)(u.x >> 16);
    acc[3] += sc * (float)(int)(signed char)(u.x >> 24);
    acc[4] += sc * (float)(int)(signed char)(u.y);
    acc[5] += sc * (float)(int)(signed char)(u.y >> 8);
    acc[6] += sc * (float)(int)(signed char)(u.y >> 16);
    acc[7] += sc * (float)(int)(signed char)(u.y >> 24);
}

// ---------------- cooperative phased aggregation (layer 1) ----------------
// grid=512 blocks x 512 threads (2 blocks/CU). Each block owns npb nodes with fp32
// accumulators in LDS. 4 phases over src-quartile windows; grid.sync() between
// phases keeps all blocks on the same (XCD-L2-resident) q8 window.
__global__ __launch_bounds__(512) void coop_agg_kernel(const uint2* __restrict__ q8,
                                                       const float* __restrict__ qs,
                                                       const int* __restrict__ start,
                                                       const uint2* __restrict__ rcnt,
                                                       const int* __restrict__ col,
                                                       const float* __restrict__ normd,
                                                       const float* __restrict__ bias,
                                                       ushort_t* __restrict__ outp,
                                                       float* __restrict__ stats,
                                                       int N, int npb) {
    extern __shared__ float sacc[];  // npb*64 floats
    cg::grid_group grid = cg::this_grid();
    int tid = threadIdx.x;
    int w = tid >> 6, lane = tid & 63;
    int g = lane >> 3, j = lane & 7;
    int base = blockIdx.x * npb;

    int totf = npb * 64;
    for (int i = tid; i < totf; i += 512) sacc[i] = 0.f;
    __syncthreads();

    for (int r = 0; r < 4; ++r) {
        for (int l = w; l < npb; l += 8) {
            int gn = base + l;
            if (gn < N) {
                uint2 rc = rcnt[gn];
                int c0 = (int)(rc.x & 0xFFFFu), c1 = (int)(rc.x >> 16);
                int c2 = (int)(rc.y & 0xFFFFu), c3 = (int)(rc.y >> 16);
                int pre, cnt;
                if (r == 0) { pre = 0; cnt = c0; }
                else if (r == 1) { pre = c0; cnt = c1; }
                else if (r == 2) { pre = c0 + c1; cnt = c2; }
                else { pre = c0 + c1 + c2; cnt = c3; }
                if (cnt > 0) {
                    int s0 = start[gn] + pre;
                    float a8[8];
#pragma unroll
                    for (int i = 0; i < 8; ++i) a8[i] = 0.f;
                    for (int k = g; k < cnt; k += 8) {
                        int c = col[s0 + k];
                        uint2 u = q8[(long long)c * 8 + j];
                        float sc = qs[c];
                        acc_i8(a8, u, sc);
                    }
#pragma unroll
                    for (int i = 0; i < 8; ++i) {
                        a8[i] += __shfl_xor(a8[i], 8, 64);
                        a8[i] += __shfl_xor(a8[i], 16, 64);
                        a8[i] += __shfl_xor(a8[i], 32, 64);
                    }
                    if (g == 0) {
#pragma unroll
                        for (int i = 0; i < 8; ++i) sacc[l * 64 + j * 8 + i] += a8[i];
                    }
                }
            }
        }
        grid.sync();
    }

    // finalize: lane = feat
    float b = bias[lane];
    float sum = 0.f, sq = 0.f;
    for (int l = w; l < npb; l += 8) {
        int gn = base + l;
        if (gn >= N) continue;
        float v = sacc[l * 64 + lane] * normd[gn] + b;
        v = v > 0.f ? v : expm1f(v);
        outp[(long long)gn * 64 + lane] = f2b(v);
        sum += v;
        sq += v * v;
    }
    __shared__ float ssum[8][64], ssq[8][64];
    ssum[w][lane] = sum;
    ssq[w][lane] = sq;
    __syncthreads();
    if (tid < 64) {
        float s = 0.f, q = 0.f;
        for (int ww = 0; ww < 8; ++ww) { s += ssum[ww][tid]; q += ssq[ww][tid]; }
        atomicAdd(&stats[tid], s);
        atomicAdd(&stats[64 + tid], q);
    }
}

// ---------------- monolithic gather-aggregate (layer 2 / control; R11-proven) ----------------
__global__ __launch_bounds__(256) void agg_fused_kernel(const uint2* __restrict__ q8,
                                                        const float* __restrict__ qs,
                                                        const int* __restrict__ start,
                                                        const int* __restrict__ degd,
                                                        const int* __restrict__ col,
                                                        const float* __restrict__ normd,
                                                        const float* __restrict__ bias,
                                                        ushort_t* __restrict__ outp,
                                                        float* __restrict__ stats, int N) {
    int tid = threadIdx.x;
    int w = tid >> 6;
    int lane = tid & 63;
    int g = lane >> 3;
    int j = lane & 7;

    float bb[8];
#pragma unroll
    for (int i = 0; i < 8; ++i) bb[i] = bias[j * 8 + i];

    float sum[8], sq[8];
#pragma unroll
    for (int i = 0; i < 8; ++i) { sum[i] = 0.f; sq[i] = 0.f; }

    for (int node = blockIdx.x * 4 + w; node < N; node += gridDim.x * 4) {
        int s0 = start[node];
        int d = degd[node];
        float acc[8];
#pragma unroll
        for (int i = 0; i < 8; ++i) acc[i] = 0.f;

        int k = 0;
        for (; k + 16 <= d; k += 16) {
            int c0 = col[s0 + k + g];
            int c1 = col[s0 + k + 8 + g];
            uint2 a = q8[(long long)c0 * 8 + j];
            uint2 b = q8[(long long)c1 * 8 + j];
            float sa = qs[c0];
            float sb = qs[c1];
            acc_i8(acc, a, sa);
            acc_i8(acc, b, sb);
        }
        for (; k + 8 <= d; k += 8) {
            int c0 = col[s0 + k + g];
            uint2 a = q8[(long long)c0 * 8 + j];
            float sa = qs[c0];
            acc_i8(acc, a, sa);
        }
        if (k < d) {
            int idx = k + g;
            if (idx < d) {
                int c0 = col[s0 + idx];
                uint2 a = q8[(long long)c0 * 8 + j];
                float sa = qs[c0];
                acc_i8(acc, a, sa);
            }
        }

#pragma unroll
        for (int i = 0; i < 8; ++i) {
            acc[i] += __shfl_xor(acc[i], 8, 64);
            acc[i] += __shfl_xor(acc[i], 16, 64);
            acc[i] += __shfl_xor(acc[i], 32, 64);
        }

        if (g == 0) {
            float nv = normd[node];
            float v[8];
#pragma unroll
            for (int i = 0; i < 8; ++i) {
                float t = acc[i] * nv + bb[i];
                t = t > 0.f ? t : expm1f(t);
                v[i] = t;
                sum[i] += t;
                sq[i] += t * t;
            }
            uint4 p;
            p.x = ((uint_t)f2b(v[1]) << 16) | f2b(v[0]);
            p.y = ((uint_t)f2b(v[3]) << 16) | f2b(v[2]);
            p.z = ((uint_t)f2b(v[5]) << 16) | f2b(v[4]);
            p.w = ((uint_t)f2b(v[7]) << 16) | f2b(v[6]);
            ((uint4*)(outp + (long long)node * 64))[j] = p;
        }
    }

    __shared__ float ssum[4][64];
    __shared__ float ssq[4][64];
    if (g == 0) {
#pragma unroll
        for (int i = 0; i < 8; ++i) {
            ssum[w][j * 8 + i] = sum[i];
            ssq[w][j * 8 + i] = sq[i];
        }
    }
    __syncthreads();
    if (tid < 64) {
        float s = ssum[0][tid] + ssum[1][tid] + ssum[2][tid] + ssum[3][tid];
        float q = ssq[0][tid] + ssq[1][tid] + ssq[2][tid] + ssq[3][tid];
        atomicAdd(&stats[tid], s);
        atomicAdd(&stats[64 + tid], q);
    }
}

// BN1 finalize + fold
__global__ __launch_bounds__(64) void bn_fin2_kernel(float* __restrict__ stats,
                                                     const float* __restrict__ gamma,
                                                     const float* __restrict__ beta,
                                                     const float* __restrict__ W2,
                                                     float* __restrict__ coef,
                                                     float* __restrict__ biasK, float inv_n) {
    int f = threadIdx.x;
    float mean = stats[f] * inv_n;
    float var = stats[64 + f] * inv_n - mean * mean;
    float a = gamma[f] * rsqrtf(var + BN_EPS);
    float cB = beta[f] - mean * a;
    coef[f] = a;
    coef[64 + f] = cB;
    stats[f] = 0.f;
    stats[64 + f] = 0.f;
    __shared__ float scB[64];
    scB[f] = cB;
    __syncthreads();
    float s = 0.f;
    for (int k = 0; k < 64; ++k) s = fmaf(scB[k], W2[k * 64 + f], s);
    biasK[f] = s;
}

__global__ __launch_bounds__(64) void bn_finalize(float* __restrict__ stats,
                                                  const float* __restrict__ gamma,
                                                  const float* __restrict__ beta,
                                                  float* __restrict__ coef, float inv_n) {
    int f = threadIdx.x;
    float mean = stats[f] * inv_n;
    float var = stats[64 + f] * inv_n - mean * mean;
    float a = gamma[f] * rsqrtf(var + BN_EPS);
    coef[f] = a;
    coef[64 + f] = beta[f] - mean * a;
}

__global__ __launch_bounds__(256) void bn_apply_b2f(const uint4* __restrict__ in,
                                                    const float* __restrict__ coef,
                                                    float4* __restrict__ out, long long n4) {
    long long i = (long long)blockIdx.x * 256 + threadIdx.x;
    if (i >= n4) return;
    int k = (int)((i & 7) << 3);
    uint4 u = in[i];
    float4 a, b;
    a.x = __uint_as_float(u.x << 16) * coef[k] + coef[64 + k];
    a.y = __uint_as_float(u.x & 0xFFFF0000u) * coef[k + 1] + coef[64 + k + 1];
    a.z = __uint_as_float(u.y << 16) * coef[k + 2] + coef[64 + k + 2];
    a.w = __uint_as_float(u.y & 0xFFFF0000u) * coef[k + 3] + coef[64 + k + 3];
    b.x = __uint_as_float(u.z << 16) * coef[k + 4] + coef[64 + k + 4];
    b.y = __uint_as_float(u.z & 0xFFFF0000u) * coef[k + 5] + coef[64 + k + 5];
    b.z = __uint_as_float(u.w << 16) * coef[k + 6] + coef[64 + k + 6];
    b.w = __uint_as_float(u.w & 0xFFFF0000u) * coef[k + 7] + coef[64 + k + 7];
    out[i * 2] = a;
    out[i * 2 + 1] = b;
}

// ---------------- launch ----------------

extern "C" void kernel_launch(void* const* d_in, const int* in_sizes, int n_in,
                              void* d_out, int out_size, void* d_ws, size_t ws_size,
                              hipStream_t stream) {
    const float* features = (const float*)d_in[0];
    const float* W1 = (const float*)d_in[1];
    const float* b1 = (const float*)d_in[2];
    const float* gamma1 = (const float*)d_in[3];
    const float* beta1 = (const float*)d_in[4];
    const float* W2 = (const float*)d_in[5];
    const float* b2 = (const float*)d_in[6];
    const float* gamma2 = (const float*)d_in[7];
    const float* beta2 = (const float*)d_in[8];
    const int* src = (const int*)d_in[9];
    const int* dst = (const int*)d_in[10];
    int N = in_sizes[0] / NFEAT_IN;
    int E = in_sizes[9];

    float inv_n = 1.0f / (float)N;
    long long tot = (long long)N * 64;
    int eblk256 = (E + 255) / 256;
    int nblk256 = (N + 255) / 256;
    int NB = (N + 127) >> 7;
    int gblk = (N + 63) / 64;
    int qblk = (N + 31) / 32;
    int Q = (N + 3) / 4;
    long long n4 = (long long)N * 8;
    int a4blk = (int)((n4 + 255) / 256);

    int npb = (N + 511) / 512;                  // nodes per coop block
    size_t ldsB = (size_t)npb * 64 * 4;
    bool useCoop = (npb <= 220);                // LDS budget guard (~56 KB)

    // workspace:
    // [curD(NB*16)|counter(4)|deg_s(N)|deg_d(N)|startv(N)|rcnt(2N)|dbuf(NB*SCAP)|col(E+8N)]
    // [floats: norm_s|norm_d|stats(128)|coef(128)|biasK(64)] [bf16 hA][bf16 oB][qs(N)][q8(N*64 i8)]
    long long bufcap = (long long)NB * SCAP;
    long long colcap = (long long)E + 8LL * N;
    long long int_total = (16LL * NB + 4 + 5LL * N + bufcap + colcap + 3) & ~3LL;
    long long flt_count = ((2LL * N + 128 + 128 + 64) + 3) & ~3LL;

    int* ip = (int*)d_ws;
    int* curD = ip;                      // stride-16 counters
    int* counter = ip + 16LL * NB;
    int* deg_s = ip + 16LL * NB + 4;
    int* deg_d = deg_s + N;
    int* startv = deg_d + N;
    uint2* rcnt = (uint2*)(startv + N);
    uint_t* dbuf = (uint_t*)(startv + N + 2LL * N);
    int* col = (int*)(dbuf + bufcap);
    float* fp = (float*)(ip + int_total);
    float* norm_s = fp;
    float* norm_d = fp + N;
    float* stats = fp + 2LL * N;
    float* coef = stats + 128;
    float* biasK = coef + 128;
    ushort_t* hA = (ushort_t*)(fp + flt_count);   // N*64 bf16 (gemm out, both layers)
    ushort_t* oB = hA + tot;                      // N*64 bf16 (agg out, both layers)
    float* qs = (float*)(oB + tot);               // N fp32 row scales
    uint2* q8 = (uint2*)(qs + ((N + 3) & ~3));    // N*64 int8 rows

    // CSR build
    hipMemsetAsync(curD, 0, sizeof(int) * (16LL * NB + 4 + N), stream);
    if (NB <= NBMAX) {
        int bblk = (E + EPB - 1) / EPB;
        block_append_kernel<<<bblk, 256, 0, stream>>>(src, dst, deg_s, curD, dbuf, E, NB);
    } else {
        deg_append_kernel<<<eblk256, 256, 0, stream>>>(src, dst, deg_s, curD, dbuf, E);
    }
    bucket_hist_kernel<<<NB, 256, 0, stream>>>(dbuf, curD, deg_d, N);
    norm_scan_kernel<<<nblk256, 256, 0, stream>>>(deg_s, deg_d, norm_s, norm_d,
                                                  startv, counter, stats, N);
    bucket_scatter2_kernel<<<NB, 256, 0, stream>>>(dbuf, curD, startv, col, rcnt, N, Q);

    // ---- layer 1 (cooperative phased agg; monolithic fallback) ----
    gemm1_mfma<<<gblk, 256, 0, stream>>>(features, W1, norm_s, hA, N);
    quant8_kernel<<<qblk, 256, 0, stream>>>(hA, q8, qs, N);
    if (useCoop) {
        const uint2* q8c = q8;
        const float* qsc = qs;
        const int* stc = startv;
        const uint2* rcc = rcnt;
        const int* colc = col;
        const float* ndc = norm_d;
        const float* b1c = b1;
        ushort_t* oBc = oB;
        float* stsc = stats;
        void* kargs[] = {(void*)&q8c, (void*)&qsc, (void*)&stc, (void*)&rcc, (void*)&colc,
                         (void*)&ndc, (void*)&b1c, (void*)&oBc, (void*)&stsc,
                         (void*)&N, (void*)&npb};
        hipLaunchCooperativeKernel((void*)coop_agg_kernel, dim3(512), dim3(512),
                                   kargs, (unsigned int)ldsB, stream);
    } else {
        agg_fused_kernel<<<2048, 256, 0, stream>>>(q8, qs, startv, deg_d, col, norm_d, b1,
                                                   oB, stats, N);
    }
    bn_fin2_kernel<<<1, 64, 0, stream>>>(stats, gamma1, beta1, W2, coef, biasK, inv_n);

    // ---- layer 2 (monolithic control) ----
    gemm2_mfma<<<gblk, 256, 0, stream>>>(oB, W2, coef, biasK, norm_s, hA, N);
    quant8_kernel<<<qblk, 256, 0, stream>>>(hA, q8, qs, N);
    agg_fused_kernel<<<2048, 256, 0, stream>>>(q8, qs, startv, deg_d, col, norm_d, b2,
                                               oB, stats, N);
    bn_finalize<<<1, 64, 0, stream>>>(stats, gamma2, beta2, coef, inv_n);
    bn_apply_b2f<<<a4blk, 256, 0, stream>>>((const uint4*)oB, coef, (float4*)d_out, n4);
}

// Round 14
// 403.385 us; speedup vs baseline: 1.7951x; 1.7951x over previous
//
#include <hip/hip_runtime.h>
#include <cmath>

#define NFEAT_IN 128
#define NFEAT_H 64
#define BN_EPS 1e-5f
#define SCAP 2560   // per-bucket capacity (mean 2046, +11 sigma)
#define EPB 8192    // edges per block in block_append
#define NBMAX 800   // LDS bucket-table limit

typedef unsigned short ushort_t;
typedef unsigned int uint_t;
typedef __attribute__((ext_vector_type(8))) short short8v;
typedef __attribute__((ext_vector_type(4))) float f32x4;

__device__ inline float b2f(ushort_t u) {
    return __uint_as_float(((uint_t)u) << 16);
}

__device__ inline ushort_t f2b(float f) {
    uint_t x = __float_as_uint(f);
    return (ushort_t)((x + 0x7FFFu + ((x >> 16) & 1u)) >> 16);  // RNE
}

// ---------------- CSR build ----------------

// Block-staged append: per-block LDS count -> per-(block,bucket) contiguous global
// reservation -> LDS-cursor placement. deg_s random histogram folded into pass 2.
__global__ __launch_bounds__(256) void block_append_kernel(const int* __restrict__ src,
                                                           const int* __restrict__ dst,
                                                           int* __restrict__ deg_s,
                                                           int* __restrict__ curD,
                                                           uint_t* __restrict__ dbuf,
                                                           int E, int NB) {
    __shared__ int lcnt[NBMAX];
    __shared__ int lcur[NBMAX];
    int t = threadIdx.x;
    int e0 = blockIdx.x * EPB;
    int e1 = min(e0 + EPB, E);
    for (int i = t; i < NB; i += 256) lcnt[i] = 0;
    __syncthreads();
    for (int e = e0 + t; e < e1; e += 256)
        atomicAdd(&lcnt[dst[e] >> 7], 1);
    __syncthreads();
    for (int i = t; i < NB; i += 256) {
        int c = lcnt[i];
        lcur[i] = (c > 0) ? atomicAdd(&curD[i * 16], c) : 0;
    }
    __syncthreads();
    for (int e = e0 + t; e < e1; e += 256) {
        int s = src[e], d = dst[e];
        atomicAdd(&deg_s[s], 1);
        int pos = atomicAdd(&lcur[d >> 7], 1);
        if (pos < SCAP) dbuf[(long long)(d >> 7) * SCAP + pos] = ((uint_t)s << 7) | (uint_t)(d & 127);
    }
}

// fallback (R9-proven) if NB > NBMAX
__global__ __launch_bounds__(256) void deg_append_kernel(const int* __restrict__ src,
                                                         const int* __restrict__ dst,
                                                         int* __restrict__ deg_s,
                                                         int* __restrict__ curD,
                                                         uint_t* __restrict__ dbuf, int E) {
    int e = blockIdx.x * 256 + threadIdx.x;
    if (e < E) {
        int s = src[e], d = dst[e];
        atomicAdd(&deg_s[s], 1);
        int pD = atomicAdd(&curD[(d >> 7) * 16], 1);
        if (pD < SCAP) dbuf[(long long)(d >> 7) * SCAP + pD] = ((uint_t)s << 7) | (uint_t)(d & 127);
    }
}

// per-bucket LDS histogram -> deg_d
__global__ __launch_bounds__(256) void bucket_hist_kernel(const uint_t* __restrict__ dbuf,
                                                          const int* __restrict__ curD,
                                                          int* __restrict__ deg_d, int N) {
    __shared__ int hist[128];
    int bb = blockIdx.x;
    int t = threadIdx.x;
    if (t < 128) hist[t] = 0;
    __syncthreads();
    int cnt = curD[bb * 16];
    if (cnt > SCAP) cnt = SCAP;
    long long base = (long long)bb * SCAP;
    for (int i = t; i < cnt; i += 256) atomicAdd(&hist[dbuf[base + i] & 127], 1);
    __syncthreads();
    if (t < 128) {
        int node = bb * 128 + t;
        if (node < N) deg_d[node] = hist[t];
    }
}

// norms + padded segment starts via block-scan (one atomic per block); zeroes stats (block 0)
__global__ __launch_bounds__(256) void norm_scan_kernel(const int* __restrict__ deg_s,
                                                        const int* __restrict__ deg_d,
                                                        float* __restrict__ norm_s,
                                                        float* __restrict__ norm_d,
                                                        int* __restrict__ start,
                                                        int* __restrict__ counter,
                                                        float* __restrict__ stats, int N) {
    int tid = threadIdx.x;
    int i = blockIdx.x * 256 + tid;
    if (blockIdx.x == 0 && tid < 128) stats[tid] = 0.f;
    int lane = tid & 63, w = tid >> 6;
    int ds = 0, dd = 0;
    if (i < N) { ds = deg_s[i]; dd = deg_d[i]; }
    int pd = (dd + 7) & ~7;

    int x = pd;
#pragma unroll
    for (int off = 1; off < 64; off <<= 1) {
        int y = __shfl_up(x, off, 64);
        if (lane >= off) x += y;
    }
    __shared__ int wsum[4];
    __shared__ int blockbase;
    if (lane == 63) wsum[w] = x;
    __syncthreads();
    if (tid == 0)
        blockbase = atomicAdd(counter, wsum[0] + wsum[1] + wsum[2] + wsum[3]);
    __syncthreads();
    int base = blockbase;
    for (int ww = 0; ww < w; ++ww) base += wsum[ww];
    int st = base + x - pd;

    if (i < N) {
        norm_s[i] = rsqrtf((float)(ds > 1 ? ds : 1));
        norm_d[i] = rsqrtf((float)(dd > 1 ? dd : 1));
        start[i] = st;
    }
}

// per-bucket scatter into col using LDS cursors (cache-local col windows)
__global__ __launch_bounds__(256) void bucket_scatter_kernel(const uint_t* __restrict__ dbuf,
                                                             const int* __restrict__ curD,
                                                             const int* __restrict__ start,
                                                             int* __restrict__ col, int N) {
    __shared__ int cur[128];
    __shared__ int sst[128];
    int b = blockIdx.x, t = threadIdx.x;
    if (t < 128) {
        cur[t] = 0;
        int node = b * 128 + t;
        sst[t] = (node < N) ? start[node] : 0;
    }
    __syncthreads();
    int cnt = curD[b * 16];
    if (cnt > SCAP) cnt = SCAP;
    long long base = (long long)b * SCAP;
    for (int i = t; i < cnt; i += 256) {
        uint_t p = dbuf[base + i];
        int d0 = (int)(p & 127u);
        int s = (int)(p >> 7);
        int off = atomicAdd(&cur[d0], 1);
        col[sst[d0] + off] = s;
    }
}

// ---------------- MFMA GEMMs (R7-verified) ----------------
// mfma_f32_16x16x32_bf16; C/D: col=lane&15, row=(lane>>4)*4+reg.

// layer 1: y[r][f] = norm[r] * (x[r][:] @ W[:][f]);  x fp32 split hi/lo, W split hi/lo (3 MFMAs)
__global__ __launch_bounds__(256) void gemm1_mfma(const float* __restrict__ x,
                                                  const float* __restrict__ W,
                                                  const float* __restrict__ norm,
                                                  ushort_t* __restrict__ out, int n) {
    constexpr int K = 128;
    __shared__ ushort_t sWh[64 * K];
    __shared__ ushort_t sWl[64 * K];
    int tid = threadIdx.x;
    for (int i = tid; i < K * 64; i += 256) {
        int k = i >> 6, f = i & 63;
        float v = W[i];
        ushort_t hi = f2b(v);
        ushort_t lo = f2b(v - b2f(hi));
        int idx = f * K + (((k >> 3) ^ (f & 7)) << 3) + (k & 7);
        sWh[idx] = hi;
        sWl[idx] = lo;
    }
    int w = tid >> 6, l = tid & 63, g = l >> 4;
    int rA = blockIdx.x * 64 + w * 16 + (l & 15);
    f32x4 acc[4];
#pragma unroll
    for (int nt = 0; nt < 4; ++nt) acc[nt] = (f32x4){0.f, 0.f, 0.f, 0.f};
    __syncthreads();

#pragma unroll
    for (int ks = 0; ks < K / 32; ++ks) {
        float av[8];
        if (rA < n) {
            const float* px = x + (long long)rA * K + ks * 32 + g * 8;
            float4 p0 = *(const float4*)px;
            float4 p1 = *(const float4*)(px + 4);
            av[0] = p0.x; av[1] = p0.y; av[2] = p0.z; av[3] = p0.w;
            av[4] = p1.x; av[5] = p1.y; av[6] = p1.z; av[7] = p1.w;
        } else {
#pragma unroll
            for (int j = 0; j < 8; ++j) av[j] = 0.f;
        }
        short8v ah, al;
#pragma unroll
        for (int j = 0; j < 8; ++j) {
            ushort_t h = f2b(av[j]);
            ah[j] = (short)h;
            al[j] = (short)f2b(av[j] - b2f(h));
        }
#pragma unroll
        for (int nt = 0; nt < 4; ++nt) {
            int f = nt * 16 + (l & 15);
            int c = (ks * 4 + g) ^ (f & 7);
            short8v bh = *(const short8v*)&sWh[f * K + (c << 3)];
            short8v bl = *(const short8v*)&sWl[f * K + (c << 3)];
            acc[nt] = __builtin_amdgcn_mfma_f32_16x16x32_bf16(ah, bh, acc[nt], 0, 0, 0);
            acc[nt] = __builtin_amdgcn_mfma_f32_16x16x32_bf16(ah, bl, acc[nt], 0, 0, 0);
            acc[nt] = __builtin_amdgcn_mfma_f32_16x16x32_bf16(al, bh, acc[nt], 0, 0, 0);
        }
    }
    int rb = blockIdx.x * 64 + w * 16 + g * 4;
    float nv[4];
#pragma unroll
    for (int j = 0; j < 4; ++j) {
        int r = rb + j;
        nv[j] = (r < n) ? norm[r] : 0.f;
    }
#pragma unroll
    for (int nt = 0; nt < 4; ++nt) {
        int cc = nt * 16 + (l & 15);
#pragma unroll
        for (int j = 0; j < 4; ++j) {
            int r = rb + j;
            if (r < n) out[(long long)r * 64 + cc] = f2b(acc[nt][j] * nv[j]);
        }
    }
}

// layer 2: y[r][f] = norm[r] * ( x[r][:] @ (cA.*W2)[:][f] + biasK[f] )
__global__ __launch_bounds__(256) void gemm2_mfma(const ushort_t* __restrict__ x,
                                                  const float* __restrict__ W,
                                                  const float* __restrict__ coef,
                                                  const float* __restrict__ biasK,
                                                  const float* __restrict__ norm,
                                                  ushort_t* __restrict__ out, int n) {
    constexpr int K = 64;
    __shared__ ushort_t sWh[64 * K];
    __shared__ ushort_t sWl[64 * K];
    int tid = threadIdx.x;
    for (int i = tid; i < K * 64; i += 256) {
        int k = i >> 6, f = i & 63;
        float v = coef[k] * W[i];
        ushort_t hi = f2b(v);
        ushort_t lo = f2b(v - b2f(hi));
        int idx = f * K + (((k >> 3) ^ (f & 7)) << 3) + (k & 7);
        sWh[idx] = hi;
        sWl[idx] = lo;
    }
    int w = tid >> 6, l = tid & 63, g = l >> 4;
    int rA = blockIdx.x * 64 + w * 16 + (l & 15);
    f32x4 acc[4];
#pragma unroll
    for (int nt = 0; nt < 4; ++nt) acc[nt] = (f32x4){0.f, 0.f, 0.f, 0.f};
    __syncthreads();

#pragma unroll
    for (int ks = 0; ks < 2; ++ks) {
        short8v ah;
        if (rA < n) {
            uint4 u = *(const uint4*)(x + (long long)rA * 64 + ks * 32 + g * 8);
            union { uint4 u; short8v s; } cvt;
            cvt.u = u;
            ah = cvt.s;
        } else {
#pragma unroll
            for (int j = 0; j < 8; ++j) ah[j] = 0;
        }
#pragma unroll
        for (int nt = 0; nt < 4; ++nt) {
            int f = nt * 16 + (l & 15);
            int c = (ks * 4 + g) ^ (f & 7);
            short8v bh = *(const short8v*)&sWh[f * K + (c << 3)];
            short8v bl = *(const short8v*)&sWl[f * K + (c << 3)];
            acc[nt] = __builtin_amdgcn_mfma_f32_16x16x32_bf16(ah, bh, acc[nt], 0, 0, 0);
            acc[nt] = __builtin_amdgcn_mfma_f32_16x16x32_bf16(ah, bl, acc[nt], 0, 0, 0);
        }
    }
    int rb = blockIdx.x * 64 + w * 16 + g * 4;
    float nv[4];
#pragma unroll
    for (int j = 0; j < 4; ++j) {
        int r = rb + j;
        nv[j] = (r < n) ? norm[r] : 0.f;
    }
#pragma unroll
    for (int nt = 0; nt < 4; ++nt) {
        int cc = nt * 16 + (l & 15);
        float bk = biasK[cc];
#pragma unroll
        for (int j = 0; j < 4; ++j) {
            int r = rb + j;
            if (r < n) out[(long long)r * 64 + cc] = f2b((acc[nt][j] + bk) * nv[j]);
        }
    }
}

// ---------------- per-row int8 quantization of h (64-B rows + fp32 scale) ----------------
__global__ __launch_bounds__(256) void quant8_kernel(const ushort_t* __restrict__ h,
                                                     uint2* __restrict__ q8,
                                                     float* __restrict__ qs, int N) {
    int tid = threadIdx.x;
    int w = tid >> 6, lane = tid & 63;
    int j = lane & 7;
    int row = blockIdx.x * 32 + w * 8 + (lane >> 3);
    if (row >= N) return;
    uint4 u = ((const uint4*)(h + (long long)row * 64))[j];
    float v[8];
    v[0] = __uint_as_float(u.x << 16);
    v[1] = __uint_as_float(u.x & 0xFFFF0000u);
    v[2] = __uint_as_float(u.y << 16);
    v[3] = __uint_as_float(u.y & 0xFFFF0000u);
    v[4] = __uint_as_float(u.z << 16);
    v[5] = __uint_as_float(u.z & 0xFFFF0000u);
    v[6] = __uint_as_float(u.w << 16);
    v[7] = __uint_as_float(u.w & 0xFFFF0000u);
    float m = 0.f;
#pragma unroll
    for (int i = 0; i < 8; ++i) m = fmaxf(m, fabsf(v[i]));
    m = fmaxf(m, __shfl_xor(m, 1, 64));
    m = fmaxf(m, __shfl_xor(m, 2, 64));
    m = fmaxf(m, __shfl_xor(m, 4, 64));
    float inv = (m > 0.f) ? 127.f / m : 0.f;
    if (j == 0) qs[row] = (m > 0.f) ? m * (1.f / 127.f) : 0.f;
    int q[8];
#pragma unroll
    for (int i = 0; i < 8; ++i) q[i] = __float2int_rn(v[i] * inv);
    uint2 p;
    p.x = (uint_t)(q[0] & 255) | ((uint_t)(q[1] & 255) << 8) |
          ((uint_t)(q[2] & 255) << 16) | ((uint_t)q[3] << 24);
    p.y = (uint_t)(q[4] & 255) | ((uint_t)(q[5] & 255) << 8) |
          ((uint_t)(q[6] & 255) << 16) | ((uint_t)q[7] << 24);
    q8[(long long)row * 8 + j] = p;
}

// ---------------- monolithic gather-aggregate over int8 h (1 line/row) ----------------
__device__ inline void acc_i8(float* acc, uint2 u, float sc) {
    acc[0] += sc * (float)(int)(signed char)(u.x);
    acc[1] += sc * (float)(int)(signed char)(u.x >> 8);
    acc[2] += sc * (float)(int)(signed char)(u.x >> 16);
    acc[3] += sc * (float)(int)(signed char)(u.x >> 24);
    acc[4] += sc * (float)(int)(signed char)(u.y);
    acc[5] += sc * (float)(int)(signed char)(u.y >> 8);
    acc[6] += sc * (float)(int)(signed char)(u.y >> 16);
    acc[7] += sc * (float)(int)(signed char)(u.y >> 24);
}

__global__ __launch_bounds__(256) void agg_fused_kernel(const uint2* __restrict__ q8,
                                                        const float* __restrict__ qs,
                                                        const int* __restrict__ start,
                                                        const int* __restrict__ degd,
                                                        const int* __restrict__ col,
                                                        const float* __restrict__ normd,
                                                        const float* __restrict__ bias,
                                                        ushort_t* __restrict__ outp,
                                                        float* __restrict__ stats, int N) {
    int tid = threadIdx.x;
    int w = tid >> 6;
    int lane = tid & 63;
    int g = lane >> 3;
    int j = lane & 7;

    float bb[8];
#pragma unroll
    for (int i = 0; i < 8; ++i) bb[i] = bias[j * 8 + i];

    float sum[8], sq[8];
#pragma unroll
    for (int i = 0; i < 8; ++i) { sum[i] = 0.f; sq[i] = 0.f; }

    for (int node = blockIdx.x * 4 + w; node < N; node += gridDim.x * 4) {
        int s0 = start[node];
        int d = degd[node];
        float acc[8];
#pragma unroll
        for (int i = 0; i < 8; ++i) acc[i] = 0.f;

        int k = 0;
        for (; k + 16 <= d; k += 16) {
            int c0 = col[s0 + k + g];
            int c1 = col[s0 + k + 8 + g];
            uint2 a = q8[(long long)c0 * 8 + j];
            uint2 b = q8[(long long)c1 * 8 + j];
            float sa = qs[c0];
            float sb = qs[c1];
            acc_i8(acc, a, sa);
            acc_i8(acc, b, sb);
        }
        for (; k + 8 <= d; k += 8) {
            int c0 = col[s0 + k + g];
            uint2 a = q8[(long long)c0 * 8 + j];
            float sa = qs[c0];
            acc_i8(acc, a, sa);
        }
        if (k < d) {
            int idx = k + g;
            if (idx < d) {
                int c0 = col[s0 + idx];
                uint2 a = q8[(long long)c0 * 8 + j];
                float sa = qs[c0];
                acc_i8(acc, a, sa);
            }
        }

#pragma unroll
        for (int i = 0; i < 8; ++i) {
            acc[i] += __shfl_xor(acc[i], 8, 64);
            acc[i] += __shfl_xor(acc[i], 16, 64);
            acc[i] += __shfl_xor(acc[i], 32, 64);
        }

        if (g == 0) {
            float nv = normd[node];
            float v[8];
#pragma unroll
            for (int i = 0; i < 8; ++i) {
                float t = acc[i] * nv + bb[i];
                t = t > 0.f ? t : expm1f(t);
                v[i] = t;
                sum[i] += t;
                sq[i] += t * t;
            }
            uint4 p;
            p.x = ((uint_t)f2b(v[1]) << 16) | f2b(v[0]);
            p.y = ((uint_t)f2b(v[3]) << 16) | f2b(v[2]);
            p.z = ((uint_t)f2b(v[5]) << 16) | f2b(v[4]);
            p.w = ((uint_t)f2b(v[7]) << 16) | f2b(v[6]);
            ((uint4*)(outp + (long long)node * 64))[j] = p;
        }
    }

    __shared__ float ssum[4][64];
    __shared__ float ssq[4][64];
    if (g == 0) {
#pragma unroll
        for (int i = 0; i < 8; ++i) {
            ssum[w][j * 8 + i] = sum[i];
            ssq[w][j * 8 + i] = sq[i];
        }
    }
    __syncthreads();
    if (tid < 64) {
        float s = ssum[0][tid] + ssum[1][tid] + ssum[2][tid] + ssum[3][tid];
        float q = ssq[0][tid] + ssq[1][tid] + ssq[2][tid] + ssq[3][tid];
        atomicAdd(&stats[tid], s);
        atomicAdd(&stats[64 + tid], q);
    }
}

// BN1 finalize + fold: coef, biasK[f] = sum_k cB[k]*W2[k][f]; resets stats
__global__ __launch_bounds__(64) void bn_fin2_kernel(float* __restrict__ stats,
                                                     const float* __restrict__ gamma,
                                                     const float* __restrict__ beta,
                                                     const float* __restrict__ W2,
                                                     float* __restrict__ coef,
                                                     float* __restrict__ biasK, float inv_n) {
    int f = threadIdx.x;
    float mean = stats[f] * inv_n;
    float var = stats[64 + f] * inv_n - mean * mean;
    float a = gamma[f] * rsqrtf(var + BN_EPS);
    float cB = beta[f] - mean * a;
    coef[f] = a;
    coef[64 + f] = cB;
    stats[f] = 0.f;
    stats[64 + f] = 0.f;
    __shared__ float scB[64];
    scB[f] = cB;
    __syncthreads();
    float s = 0.f;
    for (int k = 0; k < 64; ++k) s = fmaf(scB[k], W2[k * 64 + f], s);
    biasK[f] = s;
}

__global__ __launch_bounds__(64) void bn_finalize(float* __restrict__ stats,
                                                  const float* __restrict__ gamma,
                                                  const float* __restrict__ beta,
                                                  float* __restrict__ coef, float inv_n) {
    int f = threadIdx.x;
    float mean = stats[f] * inv_n;
    float var = stats[64 + f] * inv_n - mean * mean;
    float a = gamma[f] * rsqrtf(var + BN_EPS);
    coef[f] = a;
    coef[64 + f] = beta[f] - mean * a;
}

// BN apply reading bf16, writing fp32 d_out. i indexes uint4 (8 feats); n4 = N*8.
__global__ __launch_bounds__(256) void bn_apply_b2f(const uint4* __restrict__ in,
                                                    const float* __restrict__ coef,
                                                    float4* __restrict__ out, long long n4) {
    long long i = (long long)blockIdx.x * 256 + threadIdx.x;
    if (i >= n4) return;
    int k = (int)((i & 7) << 3);
    uint4 u = in[i];
    float4 a, b;
    a.x = __uint_as_float(u.x << 16) * coef[k] + coef[64 + k];
    a.y = __uint_as_float(u.x & 0xFFFF0000u) * coef[k + 1] + coef[64 + k + 1];
    a.z = __uint_as_float(u.y << 16) * coef[k + 2] + coef[64 + k + 2];
    a.w = __uint_as_float(u.y & 0xFFFF0000u) * coef[k + 3] + coef[64 + k + 3];
    b.x = __uint_as_float(u.z << 16) * coef[k + 4] + coef[64 + k + 4];
    b.y = __uint_as_float(u.z & 0xFFFF0000u) * coef[k + 5] + coef[64 + k + 5];
    b.z = __uint_as_float(u.w << 16) * coef[k + 6] + coef[64 + k + 6];
    b.w = __uint_as_float(u.w & 0xFFFF0000u) * coef[k + 7] + coef[64 + k + 7];
    out[i * 2] = a;
    out[i * 2 + 1] = b;
}

// ---------------- launch ----------------

extern "C" void kernel_launch(void* const* d_in, const int* in_sizes, int n_in,
                              void* d_out, int out_size, void* d_ws, size_t ws_size,
                              hipStream_t stream) {
    const float* features = (const float*)d_in[0];
    const float* W1 = (const float*)d_in[1];
    const float* b1 = (const float*)d_in[2];
    const float* gamma1 = (const float*)d_in[3];
    const float* beta1 = (const float*)d_in[4];
    const float* W2 = (const float*)d_in[5];
    const float* b2 = (const float*)d_in[6];
    const float* gamma2 = (const float*)d_in[7];
    const float* beta2 = (const float*)d_in[8];
    const int* src = (const int*)d_in[9];
    const int* dst = (const int*)d_in[10];
    int N = in_sizes[0] / NFEAT_IN;
    int E = in_sizes[9];

    float inv_n = 1.0f / (float)N;
    long long tot = (long long)N * 64;
    int eblk256 = (E + 255) / 256;
    int nblk256 = (N + 255) / 256;
    int NB = (N + 127) >> 7;
    int gblk = (N + 63) / 64;
    int qblk = (N + 31) / 32;
    long long n4 = (long long)N * 8;
    int a4blk = (int)((n4 + 255) / 256);

    // workspace:
    // [curD(NB*16) | counter(4) | deg_s(N) | deg_d(N) | startv(N) | dbuf(NB*SCAP) | col(E+8N)]
    // [floats: norm_s|norm_d|stats(128)|coef(128)|biasK(64)] [bf16 hA][bf16 oB][qs(N f32)][q8(N*64 i8)]
    long long bufcap = (long long)NB * SCAP;
    long long colcap = (long long)E + 8LL * N;
    long long int_total = (16LL * NB + 4 + 3LL * N + bufcap + colcap + 3) & ~3LL;
    long long flt_count = ((2LL * N + 128 + 128 + 64) + 3) & ~3LL;

    int* ip = (int*)d_ws;
    int* curD = ip;                      // stride-16 counters
    int* counter = ip + 16LL * NB;
    int* deg_s = ip + 16LL * NB + 4;
    int* deg_d = deg_s + N;
    int* startv = deg_d + N;
    uint_t* dbuf = (uint_t*)(startv + N);
    int* col = (int*)(dbuf + bufcap);
    float* fp = (float*)(ip + int_total);
    float* norm_s = fp;
    float* norm_d = fp + N;
    float* stats = fp + 2LL * N;
    float* coef = stats + 128;
    float* biasK = coef + 128;
    ushort_t* hA = (ushort_t*)(fp + flt_count);   // N*64 bf16 (gemm out, both layers)
    ushort_t* oB = hA + tot;                      // N*64 bf16 (agg out, both layers)
    float* qs = (float*)(oB + tot);               // N fp32 row scales
    uint2* q8 = (uint2*)(qs + ((N + 3) & ~3));    // N*64 int8 rows

    // CSR build (one memset covers curD, counter, deg_s)
    hipMemsetAsync(curD, 0, sizeof(int) * (16LL * NB + 4 + N), stream);
    if (NB <= NBMAX) {
        int bblk = (E + EPB - 1) / EPB;
        block_append_kernel<<<bblk, 256, 0, stream>>>(src, dst, deg_s, curD, dbuf, E, NB);
    } else {
        deg_append_kernel<<<eblk256, 256, 0, stream>>>(src, dst, deg_s, curD, dbuf, E);
    }
    bucket_hist_kernel<<<NB, 256, 0, stream>>>(dbuf, curD, deg_d, N);
    norm_scan_kernel<<<nblk256, 256, 0, stream>>>(deg_s, deg_d, norm_s, norm_d,
                                                  startv, counter, stats, N);
    bucket_scatter_kernel<<<NB, 256, 0, stream>>>(dbuf, curD, startv, col, N);

    // ---- layer 1 ----
    gemm1_mfma<<<gblk, 256, 0, stream>>>(features, W1, norm_s, hA, N);
    quant8_kernel<<<qblk, 256, 0, stream>>>(hA, q8, qs, N);
    agg_fused_kernel<<<2048, 256, 0, stream>>>(q8, qs, startv, deg_d, col, norm_d, b1,
                                               oB, stats, N);
    bn_fin2_kernel<<<1, 64, 0, stream>>>(stats, gamma1, beta1, W2, coef, biasK, inv_n);

    // ---- layer 2 (BN1 folded into W2' and biasK) ----
    gemm2_mfma<<<gblk, 256, 0, stream>>>(oB, W2, coef, biasK, norm_s, hA, N);
    quant8_kernel<<<qblk, 256, 0, stream>>>(hA, q8, qs, N);
    agg_fused_kernel<<<2048, 256, 0, stream>>>(q8, qs, startv, deg_d, col, norm_d, b2,
                                               oB, stats, N);
    bn_finalize<<<1, 64, 0, stream>>>(stats, gamma2, beta2, coef, inv_n);
    bn_apply_b2f<<<a4blk, 256, 0, stream>>>((const uint4*)oB, coef, (float4*)d_out, n4);
}